// Round 3
// baseline (159.264 us; speedup 1.0000x reference)
//
#include <hip/hip_runtime.h>

// GroupKAN: B=131072 rows, F=64 in-features, G=8 groups x GS=8, NB=16 RBF
// centers, O=64 outputs/group -> 512 out-features, then BatchNorm over batch.
// indices == arange(64).reshape(8,8) -> pure reshape, no gather needed.
//
// Schedule: compute-twice, write-once.
//   pass0: stream x, compute proj on the fly, accumulate per-feature sum/sumsq
//   finalize: 1 block -> scale/shift
//   pass1: recompute proj (x re-served from L3), apply BN affine, nt-store out

#define B_ROWS 131072
#define NFEAT  64
#define NGRP   8
#define GSZ    8
#define NBAS   16
#define NJ     512          // G*O output features
#define BN_EPS 1e-5f

#define CHUNK  16           // rows staged in LDS per barrier (2 rows/thread)
#define NBLOCKS 1024
#define ROWS_PER_BLOCK (B_ROWS / NBLOCKS)   // 128
#define NCHUNK (ROWS_PER_BLOCK / CHUNK)     // 8

// ws layout (floats): [0:512) sums, [512:1024) sumsq, [1024:1536) scale,
// [1536:2048) shift
template <int PASS>
__global__ __launch_bounds__(512)
void kan_pass(const float* __restrict__ x,
              const float* __restrict__ centres,
              const float* __restrict__ log_widths,
              const float* __restrict__ rbf_w,
              const float* __restrict__ lin_w,
              const float* __restrict__ proj_w,
              const float* __restrict__ proj_b,
              float* __restrict__ ws,
              float* __restrict__ out)
{
    __shared__ float s_rbf[2][CHUNK][NFEAT];   // 8 KB

    const int t  = threadIdx.x;
    const int r  = t >> 6;        // phase A: row within half-chunk (0..7)
    const int c  = t & 63;        // phase A: input column (0..63)
    const int gc = c >> 3;        // group of this column
    const int g  = t >> 6;        // phase B: output group (0..7)

    // RBF params for column-group gc, in registers.
    // w*exp(-0.5*((x-c)/sigma)^2) == w * exp2(A*(x-c)^2), A = -0.5*log2e/sigma^2
    float cc[NBAS], A[NBAS], w[NBAS];
#pragma unroll
    for (int nb = 0; nb < NBAS; ++nb) {
        cc[nb] = centres[gc * NBAS + nb];
        const float is = 1.0f / (__expf(log_widths[gc * NBAS + nb]) + 1e-6f);
        A[nb]  = -0.72134752f * is * is;   // -0.5 * log2(e) / sigma^2
        w[nb]  = rbf_w[gc * NBAS + nb];
    }
    const float lw = lin_w[gc];

    // projection weights for output feature j = t (g = t>>6, o = t&63)
    float pw[GSZ];
#pragma unroll
    for (int s = 0; s < GSZ; ++s) pw[s] = proj_w[t * GSZ + s];
    const float pb = proj_b[t];

    float scale = 0.0f, shift = 0.0f;
    if (PASS == 1) { scale = ws[1024 + t]; shift = ws[1536 + t]; }

    float fsum = 0.0f, fsq = 0.0f;
    const int row0 = blockIdx.x * ROWS_PER_BLOCK;

    // preload chunk 0's two rows for this thread
    float xv0 = x[(size_t)(row0 + r)      * NFEAT + c];
    float xv1 = x[(size_t)(row0 + r + 8)  * NFEAT + c];

    for (int ch = 0; ch < NCHUNK; ++ch) {
        const int buf = ch & 1;
        const int rowbase = row0 + ch * CHUNK;

        // ---- prefetch next chunk (issues before exp chain; latency hidden
        //      under phase A compute + barrier + phase B) ----
        float nx0 = 0.0f, nx1 = 0.0f;
        if (ch + 1 < NCHUNK) {
            nx0 = x[(size_t)(rowbase + CHUNK + r)     * NFEAT + c];
            nx1 = x[(size_t)(rowbase + CHUNK + r + 8) * NFEAT + c];
        }

        // ---- phase A: rbf_out for 2 rows -> LDS ----
        float acc0 = lw * xv0;
        float acc1 = lw * xv1;
#pragma unroll
        for (int nb = 0; nb < NBAS; ++nb) {
            const float d0 = xv0 - cc[nb];
            const float d1 = xv1 - cc[nb];
            acc0 += w[nb] * exp2f(A[nb] * d0 * d0);   // v_exp_f32
            acc1 += w[nb] * exp2f(A[nb] * d1 * d1);
        }
        s_rbf[buf][r][c]     = acc0;
        s_rbf[buf][r + 8][c] = acc1;

        __syncthreads();   // one barrier/chunk; dbuf protects prior readers

        // ---- phase B: proj for feature j = t over 16 rows ----
#pragma unroll
        for (int rr = 0; rr < CHUNK; ++rr) {
            // all 64 lanes of this wave read the same addresses: broadcast
            const float4 v0 = *reinterpret_cast<const float4*>(&s_rbf[buf][rr][g * GSZ]);
            const float4 v1 = *reinterpret_cast<const float4*>(&s_rbf[buf][rr][g * GSZ + 4]);
            float p = pb;
            p += v0.x * pw[0] + v0.y * pw[1] + v0.z * pw[2] + v0.w * pw[3];
            p += v1.x * pw[4] + v1.y * pw[5] + v1.z * pw[6] + v1.w * pw[7];
            if (PASS == 0) {
                fsum += p;
                fsq  += p * p;
            } else {
                // nontemporal: don't let the 268 MB out stream evict x from L3
                __builtin_nontemporal_store(p * scale + shift,
                    &out[(size_t)(rowbase + rr) * NJ + t]);
            }
        }

        xv0 = nx0;
        xv1 = nx1;
    }

    if (PASS == 0) {
        atomicAdd(&ws[t],       fsum);
        atomicAdd(&ws[512 + t], fsq);
    }
}

__global__ __launch_bounds__(512)
void kan_finalize(const float* __restrict__ bn_gamma,
                  const float* __restrict__ bn_beta,
                  float* __restrict__ ws)
{
    const int j = threadIdx.x;
    const float inv_b = 1.0f / (float)B_ROWS;
    const float mean  = ws[j] * inv_b;
    float var = ws[512 + j] * inv_b - mean * mean;
    var = fmaxf(var, 0.0f);
    const float sc = bn_gamma[j] * rsqrtf(var + BN_EPS);
    ws[1024 + j] = sc;
    ws[1536 + j] = bn_beta[j] - mean * sc;
}

extern "C" void kernel_launch(void* const* d_in, const int* in_sizes, int n_in,
                              void* d_out, int out_size, void* d_ws, size_t ws_size,
                              hipStream_t stream)
{
    const float* x           = (const float*)d_in[0];
    const float* centres     = (const float*)d_in[1];
    const float* log_widths  = (const float*)d_in[2];
    const float* rbf_weights = (const float*)d_in[3];
    const float* linear_w    = (const float*)d_in[4];
    const float* proj_w      = (const float*)d_in[5];
    const float* proj_b      = (const float*)d_in[6];
    const float* bn_gamma    = (const float*)d_in[7];
    const float* bn_beta     = (const float*)d_in[8];
    // d_in[9] = indices: identity arange(64) reshape -> not needed

    float* ws  = (float*)d_ws;
    float* out = (float*)d_out;

    // zero the sum/sumsq accumulators (first 1024 floats)
    (void)hipMemsetAsync(ws, 0, 1024 * sizeof(float), stream);

    kan_pass<0><<<NBLOCKS, 512, 0, stream>>>(x, centres, log_widths, rbf_weights,
                                             linear_w, proj_w, proj_b, ws, out);
    kan_finalize<<<1, 512, 0, stream>>>(bn_gamma, bn_beta, ws);
    kan_pass<1><<<NBLOCKS, 512, 0, stream>>>(x, centres, log_widths, rbf_weights,
                                             linear_w, proj_w, proj_b, ws, out);
}

// Round 5
// 144.066 us; speedup vs baseline: 1.1055x; 1.1055x over previous
//
#include <hip/hip_runtime.h>

// GroupKAN: B=131072, F=64 in-features, G=8 groups x GS=8, NB=16 RBF centers,
// O=64 outputs/group -> 512 out-features, then BatchNorm over batch.
// indices == arange(64) -> pure reshape.
//
// Key identity: BN batch statistics commute through the linear projection.
//   sum_b p[b,j]   = pw_j . S1[g]  + B*pb_j
//   sum_b p[b,j]^2 = pw_j^T M[g] pw_j + 2*pb_j*(pw_j . S1[g]) + B*pb_j^2
// with S1[g,s] = sum_b r[b,g,s],  M[g][s,s'] = sum_b r[b,g,s]*r[b,g,s'].
// So pass0 only accumulates 8*(8+64) = 576 scalars -> no proj, no LDS phase B.
// pass1 recomputes rbf (cheap) and writes out with BN affine applied: one wave
// per row, cross-lane slice gather via shuffles, zero LDS, zero barriers.

#define B_ROWS 131072
#define NFEAT  64
#define NJ     512
#define NBAS   16
#define BN_EPS 1e-5f

// ws float layout:
//   [1024:1536) scale   [1536:2048) shift
//   [2048:2624) moments: idx = c*9 + k ; c=0..63 (col), k<8: M_c[k], k=8: S1_c
//   M_c[k] = sum_b r_c * r_{(c&~7) + ((c&7)^k)}

// ---------------- pass 0: moment accumulation ----------------
// 512 blocks x 512 threads; block covers 256 rows; thread = (col c, row-sub).
__global__ __launch_bounds__(512)
void kan_moments(const float* __restrict__ x,
                 const float* __restrict__ centres,
                 const float* __restrict__ log_widths,
                 const float* __restrict__ rbf_w,
                 const float* __restrict__ lin_w,
                 float* __restrict__ ws)
{
    __shared__ float s_red[8][576];

    const int t   = threadIdx.x;
    const int c   = t & 63;       // column (lane)
    const int sub = t >> 6;       // row sub-slot (wave id in block)
    const int g   = c >> 3;       // group of this column

    float cc[NBAS], A[NBAS], w[NBAS];
#pragma unroll
    for (int nb = 0; nb < NBAS; ++nb) {
        cc[nb] = centres[g * NBAS + nb];
        const float is = 1.0f / (__expf(log_widths[g * NBAS + nb]) + 1e-6f);
        A[nb]  = -0.72134752f * is * is;     // -0.5*log2(e)/sigma^2
        w[nb]  = rbf_w[g * NBAS + nb];
    }
    const float lw = lin_w[g];

    float S1 = 0.0f;
    float M[8] = {0.f, 0.f, 0.f, 0.f, 0.f, 0.f, 0.f, 0.f};

    const int row0 = blockIdx.x * 256 + sub;
    float xv = x[(size_t)row0 * NFEAT + c];

    for (int i = 0; i < 32; ++i) {
        const float nxv = (i + 1 < 32)
            ? x[(size_t)(row0 + (i + 1) * 8) * NFEAT + c] : 0.0f;

        float r = lw * xv;
#pragma unroll
        for (int nb = 0; nb < NBAS; ++nb) {
            const float d = xv - cc[nb];
            r += w[nb] * exp2f(A[nb] * d * d);
        }
        S1 += r;
#pragma unroll
        for (int k = 0; k < 8; ++k)
            M[k] += r * __shfl_xor(r, k);   // k=0 gives r^2; stays in 8-lane grp

        xv = nxv;
    }

#pragma unroll
    for (int k = 0; k < 8; ++k) s_red[sub][c * 9 + k] = M[k];
    s_red[sub][c * 9 + 8] = S1;
    __syncthreads();

    // 576 entries, 512 threads -> strided loop (round 4 bug: `if (t<576)`
    // left entries 512..575 un-reduced; group 7's var was garbage)
    for (int idx = t; idx < 576; idx += 512) {
        float v = 0.0f;
#pragma unroll
        for (int s2 = 0; s2 < 8; ++s2) v += s_red[s2][idx];
        atomicAdd(&ws[2048 + idx], v);
    }
}

// ---------------- finalize: 576 moments -> scale/shift ----------------
__global__ __launch_bounds__(512)
void kan_finalize(const float* __restrict__ proj_w,
                  const float* __restrict__ proj_b,
                  const float* __restrict__ bn_gamma,
                  const float* __restrict__ bn_beta,
                  float* __restrict__ ws)
{
    const int j = threadIdx.x;      // 0..511
    const int g = j >> 6;

    double pw[8];
#pragma unroll
    for (int s = 0; s < 8; ++s) pw[s] = (double)proj_w[j * 8 + s];
    const double pb = (double)proj_b[j];

    double dotS1 = 0.0;
#pragma unroll
    for (int s = 0; s < 8; ++s)
        dotS1 += pw[s] * (double)ws[2048 + (g * 8 + s) * 9 + 8];

    double q = 0.0;
#pragma unroll
    for (int s = 0; s < 8; ++s) {
        double acc = 0.0;
#pragma unroll
        for (int sp = 0; sp < 8; ++sp)
            acc += pw[sp] * (double)ws[2048 + (g * 8 + s) * 9 + (s ^ sp)];
        q += pw[s] * acc;
    }

    const double Bd    = (double)B_ROWS;
    const double sum   = dotS1 + Bd * pb;
    const double sumsq = q + 2.0 * pb * dotS1 + Bd * pb * pb;
    const double mean  = sum / Bd;
    double var = sumsq / Bd - mean * mean;
    if (var < 0.0) var = 0.0;
    const double sc = (double)bn_gamma[j] / sqrt(var + (double)BN_EPS);
    ws[1024 + j] = (float)sc;
    ws[1536 + j] = (float)((double)bn_beta[j] - mean * sc);
}

// ---------------- pass 1: recompute + BN affine + write ----------------
// One wave per row; 16 sequential rows per wave. Lane l: rbf for column l,
// shuffle-gather its group's 8-slot slice, 8 output features, 2x float4 store.
__global__ __launch_bounds__(256)
void kan_write(const float* __restrict__ x,
               const float* __restrict__ centres,
               const float* __restrict__ log_widths,
               const float* __restrict__ rbf_w,
               const float* __restrict__ lin_w,
               const float* __restrict__ proj_w,
               const float* __restrict__ proj_b,
               const float* __restrict__ ws,
               float* __restrict__ out)
{
    const int l    = threadIdx.x & 63;
    const int wv   = (blockIdx.x * 256 + threadIdx.x) >> 6;   // 0..8191
    const int g    = l >> 3;
    const int base = l & ~7;

    float cc[NBAS], A[NBAS], w[NBAS];
#pragma unroll
    for (int nb = 0; nb < NBAS; ++nb) {
        cc[nb] = centres[g * NBAS + nb];
        const float is = 1.0f / (__expf(log_widths[g * NBAS + nb]) + 1e-6f);
        A[nb]  = -0.72134752f * is * is;
        w[nb]  = rbf_w[g * NBAS + nb];
    }
    const float lw = lin_w[g];

    // 8 output features j = l*8 + f
    float pw[8][8];
#pragma unroll
    for (int f = 0; f < 8; ++f)
#pragma unroll
        for (int s = 0; s < 8; ++s)
            pw[f][s] = proj_w[l * 64 + f * 8 + s];

    float sc[8], sh[8];
#pragma unroll
    for (int f = 0; f < 8; ++f) {
        sc[f] = ws[1024 + l * 8 + f];
        // fold proj bias into the shift: (p+pb)*sc+shift = p*sc + (pb*sc+shift)
        sh[f] = ws[1536 + l * 8 + f] + proj_b[l * 8 + f] * sc[f];
    }

    const int row0 = wv * 16;
    float xv = x[(size_t)row0 * NFEAT + l];

    for (int i = 0; i < 16; ++i) {
        const int row = row0 + i;
        const float nxv = (i + 1 < 16)
            ? x[(size_t)(row + 1) * NFEAT + l] : 0.0f;

        float r = lw * xv;
#pragma unroll
        for (int nb = 0; nb < NBAS; ++nb) {
            const float d = xv - cc[nb];
            r += w[nb] * exp2f(A[nb] * d * d);
        }

        float v[8];
#pragma unroll
        for (int s = 0; s < 8; ++s) v[s] = __shfl(r, base + s);

        float res[8];
#pragma unroll
        for (int f = 0; f < 8; ++f) {
            float p = v[0] * pw[f][0] + v[1] * pw[f][1] + v[2] * pw[f][2]
                    + v[3] * pw[f][3] + v[4] * pw[f][4] + v[5] * pw[f][5]
                    + v[6] * pw[f][6] + v[7] * pw[f][7];
            res[f] = p * sc[f] + sh[f];
        }

        float* o = &out[(size_t)row * NJ + l * 8];
        *reinterpret_cast<float4*>(o)     = make_float4(res[0], res[1], res[2], res[3]);
        *reinterpret_cast<float4*>(o + 4) = make_float4(res[4], res[5], res[6], res[7]);

        xv = nxv;
    }
}

extern "C" void kernel_launch(void* const* d_in, const int* in_sizes, int n_in,
                              void* d_out, int out_size, void* d_ws, size_t ws_size,
                              hipStream_t stream)
{
    const float* x           = (const float*)d_in[0];
    const float* centres     = (const float*)d_in[1];
    const float* log_widths  = (const float*)d_in[2];
    const float* rbf_weights = (const float*)d_in[3];
    const float* linear_w    = (const float*)d_in[4];
    const float* proj_w      = (const float*)d_in[5];
    const float* proj_b      = (const float*)d_in[6];
    const float* bn_gamma    = (const float*)d_in[7];
    const float* bn_beta     = (const float*)d_in[8];
    // d_in[9] = indices: identity arange -> unused

    float* ws  = (float*)d_ws;
    float* out = (float*)d_out;

    // zero moment accumulators ws[2048:2624) (and scale/shift region for hygiene)
    (void)hipMemsetAsync(ws + 1024, 0, (1024 + 576) * sizeof(float), stream);

    kan_moments <<<512, 512, 0, stream>>>(x, centres, log_widths, rbf_weights,
                                          linear_w, ws);
    kan_finalize<<<1, 512, 0, stream>>>(proj_w, proj_b, bn_gamma, bn_beta, ws);
    kan_write   <<<2048, 256, 0, stream>>>(x, centres, log_widths, rbf_weights,
                                           linear_w, proj_w, proj_b, ws, out);
}

// Round 7
// 137.628 us; speedup vs baseline: 1.1572x; 1.0468x over previous
//
#include <hip/hip_runtime.h>

// GroupKAN: B=131072, F=64 in-features, G=8 groups x GS=8, NB=16 RBF centers,
// O=64 outputs/group -> 512 out-features, then BatchNorm over batch.
// indices == arange(64) -> pure reshape.
//
// BN stats commute through the linear projection:
//   sum_b p[b,j]   = pw_j . S1[g]  + B*pb_j
//   sum_b p[b,j]^2 = pw_j^T M[g] pw_j + 2*pb_j*(pw_j . S1[g]) + B*pb_j^2
// so pass0 accumulates only 576 scalars (S1 + XOR-indexed second moments).
//
// NOTE on exp: harness compiles -O3 WITHOUT fast-math, so exp2f/expf lower to
// v_exp_f32 + denormal-range fixup (~6 instrs). __expf is the raw native
// path (v_mul log2e + v_exp_f32, 2 instrs); args are <= 0 here so FTZ is fine.

#define B_ROWS 131072
#define NFEAT  64
#define NJ     512
#define NBAS   16
#define BN_EPS 1e-5f

typedef float f32x4 __attribute__((ext_vector_type(4)));   // native vec for nt-store

// ws float layout:
//   [1024:1536) scale   [1536:2048) shift
//   [2048:2624) moments: idx = c*9 + k ; c=0..63 (col), k<8: M_c[k], k=8: S1_c
//   M_c[k] = sum_b r_c * r_{(c&~7) + ((c&7)^k)}

// ---------------- pass 0: moment accumulation ----------------
// 512 blocks x 512 threads; block covers 256 rows; thread = (col c, row-sub).
__global__ __launch_bounds__(512)
void kan_moments(const float* __restrict__ x,
                 const float* __restrict__ centres,
                 const float* __restrict__ log_widths,
                 const float* __restrict__ rbf_w,
                 const float* __restrict__ lin_w,
                 float* __restrict__ ws)
{
    __shared__ float s_red[8][576];

    const int t   = threadIdx.x;
    const int c   = t & 63;       // column (lane)
    const int sub = t >> 6;       // row sub-slot (wave id in block)
    const int g   = c >> 3;       // group of this column

    float cc[NBAS], A[NBAS], w[NBAS];
#pragma unroll
    for (int nb = 0; nb < NBAS; ++nb) {
        cc[nb] = centres[g * NBAS + nb];
        const float is = 1.0f / (__expf(log_widths[g * NBAS + nb]) + 1e-6f);
        A[nb]  = -0.5f * is * is;            // natural-log coefficient
        w[nb]  = rbf_w[g * NBAS + nb];
    }
    const float lw = lin_w[g];

    float S1 = 0.0f;
    float M[8] = {0.f, 0.f, 0.f, 0.f, 0.f, 0.f, 0.f, 0.f};

    const int row0 = blockIdx.x * 256 + sub;
    float xv = x[(size_t)row0 * NFEAT + c];

    for (int i = 0; i < 32; ++i) {
        const float nxv = (i + 1 < 32)
            ? x[(size_t)(row0 + (i + 1) * 8) * NFEAT + c] : 0.0f;

        float r = lw * xv;
#pragma unroll
        for (int nb = 0; nb < NBAS; ++nb) {
            const float d = xv - cc[nb];
            r += w[nb] * __expf(A[nb] * d * d);   // v_mul + v_exp_f32
        }
        S1 += r;
#pragma unroll
        for (int k = 0; k < 8; ++k)
            M[k] += r * __shfl_xor(r, k);   // k=0 gives r^2; stays in 8-lane grp

        xv = nxv;
    }

#pragma unroll
    for (int k = 0; k < 8; ++k) s_red[sub][c * 9 + k] = M[k];
    s_red[sub][c * 9 + 8] = S1;
    __syncthreads();

    // 576 entries, 512 threads -> strided loop
    for (int idx = t; idx < 576; idx += 512) {
        float v = 0.0f;
#pragma unroll
        for (int s2 = 0; s2 < 8; ++s2) v += s_red[s2][idx];
        atomicAdd(&ws[2048 + idx], v);
    }
}

// ---------------- finalize: 576 moments -> scale/shift ----------------
__global__ __launch_bounds__(512)
void kan_finalize(const float* __restrict__ proj_w,
                  const float* __restrict__ proj_b,
                  const float* __restrict__ bn_gamma,
                  const float* __restrict__ bn_beta,
                  float* __restrict__ ws)
{
    const int j = threadIdx.x;      // 0..511
    const int g = j >> 6;

    double pw[8];
#pragma unroll
    for (int s = 0; s < 8; ++s) pw[s] = (double)proj_w[j * 8 + s];
    const double pb = (double)proj_b[j];

    double dotS1 = 0.0;
#pragma unroll
    for (int s = 0; s < 8; ++s)
        dotS1 += pw[s] * (double)ws[2048 + (g * 8 + s) * 9 + 8];

    double q = 0.0;
#pragma unroll
    for (int s = 0; s < 8; ++s) {
        double acc = 0.0;
#pragma unroll
        for (int sp = 0; sp < 8; ++sp)
            acc += pw[sp] * (double)ws[2048 + (g * 8 + s) * 9 + (s ^ sp)];
        q += pw[s] * acc;
    }

    const double Bd    = (double)B_ROWS;
    const double sum   = dotS1 + Bd * pb;
    const double sumsq = q + 2.0 * pb * dotS1 + Bd * pb * pb;
    const double mean  = sum / Bd;
    double var = sumsq / Bd - mean * mean;
    if (var < 0.0) var = 0.0;
    const double sc = (double)bn_gamma[j] / sqrt(var + (double)BN_EPS);
    ws[1024 + j] = (float)sc;
    ws[1536 + j] = (float)((double)bn_beta[j] - mean * sc);
}

// ---------------- pass 1: recompute + BN affine + write ----------------
// One wave per 16 rows, processed in pairs for load/exp ILP. Lane l: rbf for
// column l, shuffle-gather its group's 8-slot slice, 8 features, nt stores.
__global__ __launch_bounds__(256)
void kan_write(const float* __restrict__ x,
               const float* __restrict__ centres,
               const float* __restrict__ log_widths,
               const float* __restrict__ rbf_w,
               const float* __restrict__ lin_w,
               const float* __restrict__ proj_w,
               const float* __restrict__ proj_b,
               const float* __restrict__ ws,
               float* __restrict__ out)
{
    const int l    = threadIdx.x & 63;
    const int wv   = (blockIdx.x * 256 + threadIdx.x) >> 6;   // 0..8191
    const int g    = l >> 3;
    const int base = l & ~7;

    float cc[NBAS], A[NBAS], w[NBAS];
#pragma unroll
    for (int nb = 0; nb < NBAS; ++nb) {
        cc[nb] = centres[g * NBAS + nb];
        const float is = 1.0f / (__expf(log_widths[g * NBAS + nb]) + 1e-6f);
        A[nb]  = -0.5f * is * is;
        w[nb]  = rbf_w[g * NBAS + nb];
    }
    const float lw = lin_w[g];

    // 8 output features j = l*8 + f
    float pw[8][8];
#pragma unroll
    for (int f = 0; f < 8; ++f)
#pragma unroll
        for (int s = 0; s < 8; ++s)
            pw[f][s] = proj_w[l * 64 + f * 8 + s];

    float sc[8], sh[8];
#pragma unroll
    for (int f = 0; f < 8; ++f) {
        sc[f] = ws[1024 + l * 8 + f];
        // fold proj bias into the shift
        sh[f] = ws[1536 + l * 8 + f] + proj_b[l * 8 + f] * sc[f];
    }

    const int row0 = wv * 16;
    float xa = x[(size_t)row0 * NFEAT + l];
    float xb = x[(size_t)(row0 + 1) * NFEAT + l];

    for (int i = 0; i < 16; i += 2) {
        const int row = row0 + i;
        float na = 0.0f, nb2 = 0.0f;
        if (i + 2 < 16) {
            na  = x[(size_t)(row + 2) * NFEAT + l];
            nb2 = x[(size_t)(row + 3) * NFEAT + l];
        }

        // two independent rbf chains -> 32 independent v_exp in flight
        float ra = lw * xa;
        float rb = lw * xb;
#pragma unroll
        for (int nb = 0; nb < NBAS; ++nb) {
            const float da = xa - cc[nb];
            const float db = xb - cc[nb];
            ra += w[nb] * __expf(A[nb] * da * da);
            rb += w[nb] * __expf(A[nb] * db * db);
        }

        float va[8], vb[8];
#pragma unroll
        for (int s = 0; s < 8; ++s) {
            va[s] = __shfl(ra, base + s);
            vb[s] = __shfl(rb, base + s);
        }

        f32x4 r0, r1, r2, r3;
#pragma unroll
        for (int f = 0; f < 4; ++f) {
            float pa0 = va[0]*pw[f][0] + va[1]*pw[f][1] + va[2]*pw[f][2]
                      + va[3]*pw[f][3] + va[4]*pw[f][4] + va[5]*pw[f][5]
                      + va[6]*pw[f][6] + va[7]*pw[f][7];
            float pa1 = va[0]*pw[f+4][0] + va[1]*pw[f+4][1] + va[2]*pw[f+4][2]
                      + va[3]*pw[f+4][3] + va[4]*pw[f+4][4] + va[5]*pw[f+4][5]
                      + va[6]*pw[f+4][6] + va[7]*pw[f+4][7];
            float pb0 = vb[0]*pw[f][0] + vb[1]*pw[f][1] + vb[2]*pw[f][2]
                      + vb[3]*pw[f][3] + vb[4]*pw[f][4] + vb[5]*pw[f][5]
                      + vb[6]*pw[f][6] + vb[7]*pw[f][7];
            float pb1 = vb[0]*pw[f+4][0] + vb[1]*pw[f+4][1] + vb[2]*pw[f+4][2]
                      + vb[3]*pw[f+4][3] + vb[4]*pw[f+4][4] + vb[5]*pw[f+4][5]
                      + vb[6]*pw[f+4][6] + vb[7]*pw[f+4][7];
            r0[f] = pa0 * sc[f]     + sh[f];
            r1[f] = pa1 * sc[f + 4] + sh[f + 4];
            r2[f] = pb0 * sc[f]     + sh[f];
            r3[f] = pb1 * sc[f + 4] + sh[f + 4];
        }

        // nontemporal: keep x resident in L3 for this pass's later reads
        float* oa = &out[(size_t)row * NJ + l * 8];
        float* ob = &out[(size_t)(row + 1) * NJ + l * 8];
        __builtin_nontemporal_store(r0, reinterpret_cast<f32x4*>(oa));
        __builtin_nontemporal_store(r1, reinterpret_cast<f32x4*>(oa + 4));
        __builtin_nontemporal_store(r2, reinterpret_cast<f32x4*>(ob));
        __builtin_nontemporal_store(r3, reinterpret_cast<f32x4*>(ob + 4));

        xa = na;
        xb = nb2;
    }
}

extern "C" void kernel_launch(void* const* d_in, const int* in_sizes, int n_in,
                              void* d_out, int out_size, void* d_ws, size_t ws_size,
                              hipStream_t stream)
{
    const float* x           = (const float*)d_in[0];
    const float* centres     = (const float*)d_in[1];
    const float* log_widths  = (const float*)d_in[2];
    const float* rbf_weights = (const float*)d_in[3];
    const float* linear_w    = (const float*)d_in[4];
    const float* proj_w      = (const float*)d_in[5];
    const float* proj_b      = (const float*)d_in[6];
    const float* bn_gamma    = (const float*)d_in[7];
    const float* bn_beta     = (const float*)d_in[8];
    // d_in[9] = indices: identity arange -> unused

    float* ws  = (float*)d_ws;
    float* out = (float*)d_out;

    // zero moment accumulators + scale/shift region
    (void)hipMemsetAsync(ws + 1024, 0, (1024 + 576) * sizeof(float), stream);

    kan_moments <<<512, 512, 0, stream>>>(x, centres, log_widths, rbf_weights,
                                          linear_w, ws);
    kan_finalize<<<1, 512, 0, stream>>>(proj_w, proj_b, bn_gamma, bn_beta, ws);
    kan_write   <<<2048, 256, 0, stream>>>(x, centres, log_widths, rbf_weights,
                                           linear_w, proj_w, proj_b, ws, out);
}

// Round 8
// 116.976 us; speedup vs baseline: 1.3615x; 1.1765x over previous
//
#include <hip/hip_runtime.h>

// GroupKAN: B=131072, F=64 in-features, G=8 groups x GS=8, NB=16 RBF centers,
// O=64 outputs/group -> 512 out-features, then BatchNorm over batch.
// indices == arange(64) -> pure reshape.
//
// BN stats commute through the linear projection:
//   sum_b p[b,j]   = pw_j . S1[g]  + B*pb_j
//   sum_b p[b,j]^2 = pw_j^T M[g] pw_j + 2*pb_j*(pw_j . S1[g]) + B*pb_j^2
// so pass0 accumulates only 576 scalars (S1 + XOR-indexed second moments).
//
// Round 8 change: kan_write stores are now LANE-LINEAR. Lane l owns features
// {4l..4l+3} and {256+4l..4l+259}, so each float4 wave-store covers a
// contiguous 1 KB of full 64-B lines (prev: 32B/lane split into 2 strided
// 16-B stores -> partial-line sectors at HBM under nt streaming).

#define B_ROWS 131072
#define NFEAT  64
#define NJ     512
#define NBAS   16
#define BN_EPS 1e-5f

typedef float f32x4 __attribute__((ext_vector_type(4)));

// ws float layout:
//   [1024:1536) scale   [1536:2048) shift
//   [2048:2624) moments: idx = c*9 + k ; c=0..63 (col), k<8: M_c[k], k=8: S1_c
//   M_c[k] = sum_b r_c * r_{(c&~7) + ((c&7)^k)}

// ---------------- pass 0: moment accumulation ----------------
__global__ __launch_bounds__(512)
void kan_moments(const float* __restrict__ x,
                 const float* __restrict__ centres,
                 const float* __restrict__ log_widths,
                 const float* __restrict__ rbf_w,
                 const float* __restrict__ lin_w,
                 float* __restrict__ ws)
{
    __shared__ float s_red[8][576];

    const int t   = threadIdx.x;
    const int c   = t & 63;       // column (lane)
    const int sub = t >> 6;       // row sub-slot (wave id in block)
    const int g   = c >> 3;       // group of this column

    float cc[NBAS], A[NBAS], w[NBAS];
#pragma unroll
    for (int nb = 0; nb < NBAS; ++nb) {
        cc[nb] = centres[g * NBAS + nb];
        const float is = 1.0f / (__expf(log_widths[g * NBAS + nb]) + 1e-6f);
        A[nb]  = -0.5f * is * is;
        w[nb]  = rbf_w[g * NBAS + nb];
    }
    const float lw = lin_w[g];

    float S1 = 0.0f;
    float M[8] = {0.f, 0.f, 0.f, 0.f, 0.f, 0.f, 0.f, 0.f};

    const int row0 = blockIdx.x * 256 + sub;
    float xv = x[(size_t)row0 * NFEAT + c];

    for (int i = 0; i < 32; ++i) {
        const float nxv = (i + 1 < 32)
            ? x[(size_t)(row0 + (i + 1) * 8) * NFEAT + c] : 0.0f;

        float r = lw * xv;
#pragma unroll
        for (int nb = 0; nb < NBAS; ++nb) {
            const float d = xv - cc[nb];
            r += w[nb] * __expf(A[nb] * d * d);
        }
        S1 += r;
#pragma unroll
        for (int k = 0; k < 8; ++k)
            M[k] += r * __shfl_xor(r, k);   // stays within the 8-lane group

        xv = nxv;
    }

#pragma unroll
    for (int k = 0; k < 8; ++k) s_red[sub][c * 9 + k] = M[k];
    s_red[sub][c * 9 + 8] = S1;
    __syncthreads();

    for (int idx = t; idx < 576; idx += 512) {
        float v = 0.0f;
#pragma unroll
        for (int s2 = 0; s2 < 8; ++s2) v += s_red[s2][idx];
        atomicAdd(&ws[2048 + idx], v);
    }
}

// ---------------- finalize: 576 moments -> scale/shift ----------------
__global__ __launch_bounds__(512)
void kan_finalize(const float* __restrict__ proj_w,
                  const float* __restrict__ proj_b,
                  const float* __restrict__ bn_gamma,
                  const float* __restrict__ bn_beta,
                  float* __restrict__ ws)
{
    const int j = threadIdx.x;      // 0..511
    const int g = j >> 6;

    double pw[8];
#pragma unroll
    for (int s = 0; s < 8; ++s) pw[s] = (double)proj_w[j * 8 + s];
    const double pb = (double)proj_b[j];

    double dotS1 = 0.0;
#pragma unroll
    for (int s = 0; s < 8; ++s)
        dotS1 += pw[s] * (double)ws[2048 + (g * 8 + s) * 9 + 8];

    double q = 0.0;
#pragma unroll
    for (int s = 0; s < 8; ++s) {
        double acc = 0.0;
#pragma unroll
        for (int sp = 0; sp < 8; ++sp)
            acc += pw[sp] * (double)ws[2048 + (g * 8 + s) * 9 + (s ^ sp)];
        q += pw[s] * acc;
    }

    const double Bd    = (double)B_ROWS;
    const double sum   = dotS1 + Bd * pb;
    const double sumsq = q + 2.0 * pb * dotS1 + Bd * pb * pb;
    const double mean  = sum / Bd;
    double var = sumsq / Bd - mean * mean;
    if (var < 0.0) var = 0.0;
    const double sc = (double)bn_gamma[j] / sqrt(var + (double)BN_EPS);
    ws[1024 + j] = (float)sc;
    ws[1536 + j] = (float)((double)bn_beta[j] - mean * sc);
}

// ---------------- pass 1: recompute + BN affine + write ----------------
// One wave per 16 rows, row pairs for ILP. Lane l computes rbf for column l;
// features are distributed lane-linearly: lane l -> {4l..4l+3, 256+4l..+3}.
__global__ __launch_bounds__(256)
void kan_write(const float* __restrict__ x,
               const float* __restrict__ centres,
               const float* __restrict__ log_widths,
               const float* __restrict__ rbf_w,
               const float* __restrict__ lin_w,
               const float* __restrict__ proj_w,
               const float* __restrict__ proj_b,
               const float* __restrict__ ws,
               float* __restrict__ out)
{
    const int l  = threadIdx.x & 63;
    const int wv = (blockIdx.x * 256 + threadIdx.x) >> 6;   // 0..8191
    const int g  = l >> 3;         // column group for the rbf compute
    const int bl = (l >> 4) * 8;   // lane base of lo-feature slice (group l>>4)
    const int bh = bl + 32;        // lane base of hi-feature slice (group l>>4 + 4)

    float cc[NBAS], A[NBAS], w[NBAS];
#pragma unroll
    for (int nb = 0; nb < NBAS; ++nb) {
        cc[nb] = centres[g * NBAS + nb];
        const float is = 1.0f / (__expf(log_widths[g * NBAS + nb]) + 1e-6f);
        A[nb]  = -0.5f * is * is;
        w[nb]  = rbf_w[g * NBAS + nb];
    }
    const float lw = lin_w[g];

    // lo features j = 4l+f, hi features j = 256+4l+f (f = 0..3)
    float pwl[4][8], pwh[4][8], scl[4], shl[4], sch[4], shh[4];
#pragma unroll
    for (int f = 0; f < 4; ++f) {
        const int jl = 4 * l + f;
        const int jh = 256 + 4 * l + f;
#pragma unroll
        for (int s = 0; s < 8; ++s) {
            pwl[f][s] = proj_w[jl * 8 + s];
            pwh[f][s] = proj_w[jh * 8 + s];
        }
        scl[f] = ws[1024 + jl];
        shl[f] = ws[1536 + jl] + proj_b[jl] * scl[f];   // fold proj bias
        sch[f] = ws[1024 + jh];
        shh[f] = ws[1536 + jh] + proj_b[jh] * sch[f];
    }

    const int row0 = wv * 16;
    float xa = x[(size_t)row0 * NFEAT + l];
    float xb = x[(size_t)(row0 + 1) * NFEAT + l];

    for (int i = 0; i < 16; i += 2) {
        const int row = row0 + i;
        float na = 0.0f, nb2 = 0.0f;
        if (i + 2 < 16) {
            na  = x[(size_t)(row + 2) * NFEAT + l];
            nb2 = x[(size_t)(row + 3) * NFEAT + l];
        }

        // two independent rbf chains -> 32 independent v_exp in flight
        float ra = lw * xa;
        float rb = lw * xb;
#pragma unroll
        for (int nb = 0; nb < NBAS; ++nb) {
            const float da = xa - cc[nb];
            const float db = xb - cc[nb];
            ra += w[nb] * __expf(A[nb] * da * da);
            rb += w[nb] * __expf(A[nb] * db * db);
        }

        // gather the two group slices this lane's features need
        float val[8], vah[8], vbl[8], vbh[8];
#pragma unroll
        for (int s = 0; s < 8; ++s) {
            val[s] = __shfl(ra, bl + s);
            vah[s] = __shfl(ra, bh + s);
            vbl[s] = __shfl(rb, bl + s);
            vbh[s] = __shfl(rb, bh + s);
        }

        f32x4 r0, r1, r2, r3;
#pragma unroll
        for (int f = 0; f < 4; ++f) {
            float pal = val[0]*pwl[f][0] + val[1]*pwl[f][1] + val[2]*pwl[f][2]
                      + val[3]*pwl[f][3] + val[4]*pwl[f][4] + val[5]*pwl[f][5]
                      + val[6]*pwl[f][6] + val[7]*pwl[f][7];
            float pah = vah[0]*pwh[f][0] + vah[1]*pwh[f][1] + vah[2]*pwh[f][2]
                      + vah[3]*pwh[f][3] + vah[4]*pwh[f][4] + vah[5]*pwh[f][5]
                      + vah[6]*pwh[f][6] + vah[7]*pwh[f][7];
            float pbl = vbl[0]*pwl[f][0] + vbl[1]*pwl[f][1] + vbl[2]*pwl[f][2]
                      + vbl[3]*pwl[f][3] + vbl[4]*pwl[f][4] + vbl[5]*pwl[f][5]
                      + vbl[6]*pwl[f][6] + vbl[7]*pwl[f][7];
            float pbh = vbh[0]*pwh[f][0] + vbh[1]*pwh[f][1] + vbh[2]*pwh[f][2]
                      + vbh[3]*pwh[f][3] + vbh[4]*pwh[f][4] + vbh[5]*pwh[f][5]
                      + vbh[6]*pwh[f][6] + vbh[7]*pwh[f][7];
            r0[f] = pal * scl[f] + shl[f];
            r1[f] = pah * sch[f] + shh[f];
            r2[f] = pbl * scl[f] + shl[f];
            r3[f] = pbh * sch[f] + shh[f];
        }

        // lane-linear nt stores: each instruction covers contiguous 1 KB
        float* oa = &out[(size_t)row * NJ];
        float* ob = &out[(size_t)(row + 1) * NJ];
        __builtin_nontemporal_store(r0, reinterpret_cast<f32x4*>(oa + 4 * l));
        __builtin_nontemporal_store(r1, reinterpret_cast<f32x4*>(oa + 256 + 4 * l));
        __builtin_nontemporal_store(r2, reinterpret_cast<f32x4*>(ob + 4 * l));
        __builtin_nontemporal_store(r3, reinterpret_cast<f32x4*>(ob + 256 + 4 * l));

        xa = na;
        xb = nb2;
    }
}

extern "C" void kernel_launch(void* const* d_in, const int* in_sizes, int n_in,
                              void* d_out, int out_size, void* d_ws, size_t ws_size,
                              hipStream_t stream)
{
    const float* x           = (const float*)d_in[0];
    const float* centres     = (const float*)d_in[1];
    const float* log_widths  = (const float*)d_in[2];
    const float* rbf_weights = (const float*)d_in[3];
    const float* linear_w    = (const float*)d_in[4];
    const float* proj_w      = (const float*)d_in[5];
    const float* proj_b      = (const float*)d_in[6];
    const float* bn_gamma    = (const float*)d_in[7];
    const float* bn_beta     = (const float*)d_in[8];
    // d_in[9] = indices: identity arange -> unused

    float* ws  = (float*)d_ws;
    float* out = (float*)d_out;

    // zero moment accumulators + scale/shift region
    (void)hipMemsetAsync(ws + 1024, 0, (1024 + 576) * sizeof(float), stream);

    kan_moments <<<512, 512, 0, stream>>>(x, centres, log_widths, rbf_weights,
                                          linear_w, ws);
    kan_finalize<<<1, 512, 0, stream>>>(proj_w, proj_b, bn_gamma, bn_beta, ws);
    kan_write   <<<2048, 256, 0, stream>>>(x, centres, log_widths, rbf_weights,
                                           linear_w, proj_w, proj_b, ws, out);
}